// Round 15
// baseline (218.586 us; speedup 1.0000x reference)
//
#include <hip/hip_runtime.h>
#include <hip/hip_bf16.h>
#include <stdint.h>

// Sizes
#define BATCH 512
#define HID   4096
#define NC    32
#define CD    64
#define CB    1024
#define NCD   2048   // NC*CD

typedef unsigned short u16;
typedef unsigned int   u32;
typedef unsigned long long u64;
typedef __attribute__((ext_vector_type(8))) short short8;  // 8 bf16
typedef __attribute__((ext_vector_type(4))) float f32x4;

#define WAVE_SYNC()  asm volatile("s_waitcnt lgkmcnt(0)" ::: "memory")
#define SCHED_FENCE() __builtin_amdgcn_sched_barrier(0)

__device__ inline u16 bf16_rne(float f) {
  u32 u = __builtin_bit_cast(u32, f);
  u32 r = u + 0x7FFFu + ((u >> 16) & 1u);
  return (u16)(r >> 16);
}
__device__ inline float bf16_f32(u16 h) {
  u32 u = ((u32)h) << 16;
  return __builtin_bit_cast(float, u);
}
__device__ inline void split3(float a, u16& h1, u16& h2, u16& h3) {
  h1 = bf16_rne(a);
  float r1 = a - bf16_f32(h1);
  h2 = bf16_rne(r1);
  float r2 = r1 - bf16_f32(h2);
  h3 = bf16_rne(r2);
}
__device__ inline f32x4 mfma16(short8 a, short8 b, f32x4 c) {
  return __builtin_amdgcn_mfma_f32_16x16x32_bf16(a, b, c, 0, 0, 0);
}
__device__ inline void gload_lds16(const u16* g, u16* l) {
  __builtin_amdgcn_global_load_lds(
      (const __attribute__((address_space(1))) u32*)(const void*)g,
      (__attribute__((address_space(3))) u32*)(void*)l, 16, 0, 0);
}

// DPP cross-lane movers (plain-VALU latency, no LDS round trip).
template<int CTRL>
__device__ inline double dpp_f64(double x) {
  u64 u = __builtin_bit_cast(u64, x);
  int lo = (int)(u32)u, hi = (int)(u32)(u >> 32);
  lo = __builtin_amdgcn_update_dpp(lo, lo, CTRL, 0xF, 0xF, true);
  hi = __builtin_amdgcn_update_dpp(hi, hi, CTRL, 0xF, 0xF, true);
  u64 r = ((u64)(u32)hi << 32) | (u64)(u32)lo;
  return __builtin_bit_cast(double, r);
}
template<int CTRL>
__device__ inline int dpp_i32(int x) {
  return __builtin_amdgcn_update_dpp(x, x, CTRL, 0xF, 0xF, true);
}

union H8 { u16 h[8]; short8 v; };

// ---------------------------------------------------------------------------
// conv_split3: f32 [ROWS][K] -> 3 bf16 fragment-blob arrays (coalesced read).
// ---------------------------------------------------------------------------
template<int K>
__global__ __launch_bounds__(256) void conv_split3(
    const float* __restrict__ src, u16* __restrict__ d1,
    u16* __restrict__ d2, u16* __restrict__ d3) {
  __shared__ float st[4][16][36];
  const int t = threadIdx.x;
  const int wv = t >> 6, l = t & 63;
  const int g = blockIdx.x * 4 + wv;
  const int rowbase = (g / (K / 32)) * 16;
  const int kbase   = (g % (K / 32)) * 32;
  {
    const float* s = src + (size_t)(rowbase + (l >> 2)) * K + kbase + (l & 3) * 8;
    *(f32x4*)&st[wv][l >> 2][(l & 3) * 8]     = *(const f32x4*)s;
    *(f32x4*)&st[wv][l >> 2][(l & 3) * 8 + 4] = *(const f32x4*)(s + 4);
  }
  __syncthreads();
  float vv[8];
  *(f32x4*)&vv[0] = *(const f32x4*)&st[wv][l & 15][(l >> 4) * 8];
  *(f32x4*)&vv[4] = *(const f32x4*)&st[wv][l & 15][(l >> 4) * 8 + 4];
  H8 o1, o2, o3;
#pragma unroll
  for (int i = 0; i < 8; ++i) split3(vv[i], o1.h[i], o2.h[i], o3.h[i]);
  size_t off = (size_t)g * 512 + l * 8;
  *(short8*)(d1 + off) = o1.v;
  *(short8*)(d2 + off) = o2.v;
  *(short8*)(d3 + off) = o3.v;
}

// ---------------------------------------------------------------------------
// conv_split1_dual: two f32 sources -> bf16 blobs in one launch (K=2048 both).
// ---------------------------------------------------------------------------
__global__ __launch_bounds__(256) void conv_split1_dual(
    const float* __restrict__ s1, u16* __restrict__ dst1,
    const float* __restrict__ s2, u16* __restrict__ dst2) {
  __shared__ float st[4][16][36];
  const int t = threadIdx.x;
  const int wv = t >> 6, l = t & 63;
  const int bb = blockIdx.x;
  const float* src; u16* dst; int g;
  if (bb < 4096) { src = s1; dst = dst1; g = bb * 4 + wv; }
  else           { src = s2; dst = dst2; g = (bb - 4096) * 4 + wv; }
  const int rowbase = (g / 64) * 16;     // K/32 = 64
  const int kbase   = (g % 64) * 32;
  {
    const float* s = src + (size_t)(rowbase + (l >> 2)) * 2048 + kbase + (l & 3) * 8;
    *(f32x4*)&st[wv][l >> 2][(l & 3) * 8]     = *(const f32x4*)s;
    *(f32x4*)&st[wv][l >> 2][(l & 3) * 8 + 4] = *(const f32x4*)(s + 4);
  }
  __syncthreads();
  float vv[8];
  *(f32x4*)&vv[0] = *(const f32x4*)&st[wv][l & 15][(l >> 4) * 8];
  *(f32x4*)&vv[4] = *(const f32x4*)&st[wv][l & 15][(l >> 4) * 8 + 4];
  H8 o1;
#pragma unroll
  for (int i = 0; i < 8; ++i) o1.h[i] = bf16_rne(vv[i]);
  *(short8*)(dst + (size_t)g * 512 + l * 8) = o1.v;
}

// ---------------------------------------------------------------------------
// k1_gemm (round 15): pure-blob bf16x3 6-term GEMM with the k3-VALIDATED
// triple-buffer counted-vmcnt pipeline. Per iter:
//   [vmcnt(9); s_barrier; issue ks+2 -> buf[(ks+2)%3]; compute buf[ks%3]]
// Each wave issues 9 loads/step -> 18 outstanding at iter top; vmcnt(9)
// waits exactly the oldest batch (buf[cur]). RAW: vmcnt-then-barrier.
// WAR: issue target (ks+2)%3 == (ks-1)%3, read finished before this barrier.
// 108 KiB LDS -> 1 block/CU; grid 512 = 2 rounds/CU.
// K-order and MFMA term order bit-identical to rounds 8-14.
// ---------------------------------------------------------------------------
__global__ __launch_bounds__(256, 1) void k1_gemm(
    const u16* __restrict__ A1, const u16* __restrict__ A2,
    const u16* __restrict__ A3,
    const u16* __restrict__ B1, const u16* __restrict__ B2,
    const u16* __restrict__ B3, float* __restrict__ part) {
  __shared__ u16 lds_all[3][36 * 512];   // 108 KiB
  const int t = threadIdx.x;
  const int wid = t >> 6, lane = t & 63;      // 4 waves
  const int wrow = wid >> 1, wcol = wid & 1;  // 2x2 wave grid
  const int d = blockIdx.x + (blockIdx.y << 2) + (blockIdx.z << 7);  // 0..511
  const int xcd = d & 7, sl = d >> 3;            // sl 0..63
  const int panel = (xcd << 4) + (sl >> 2);      // 0..127
  const int bm = (sl & 3) * 128;
  const int bn_t = panel & 31;                   // 64-col tile id
  const int kz = panel >> 5;                     // 0..3
  const int ks0 = kz * 32;                       // 32 ksteps per kz

  const u16* gp[9];
#pragma unroll
  for (int i = 0; i < 9; ++i) {
    const int b = wid + 4 * i;
    const u16* base;
    size_t frag;
    if (b < 24) {
      const int s = b >> 3, rf = b & 7;
      base = (s == 0) ? A1 : (s == 1) ? A2 : A3;
      frag = (size_t)((bm >> 4) + rf);
    } else {
      const int bb = b - 24;
      const int s = bb >> 2, cf = bb & 3;
      base = (s == 0) ? B1 : (s == 1) ? B2 : B3;
      frag = (size_t)(bn_t * 4 + cf);
    }
    gp[i] = base + (frag * 128 + ks0) * 512 + lane * 8;
  }

  f32x4 acc[4][2];
#pragma unroll
  for (int r = 0; r < 4; ++r)
#pragma unroll
    for (int c = 0; c < 2; ++c) acc[r][c] = (f32x4)0.f;

  // prologue: issue ksteps 0,1 into bufs 0,1
#pragma unroll
  for (int p = 0; p < 2; ++p) {
#pragma unroll
    for (int i = 0; i < 9; ++i) {
      gload_lds16(gp[i], &lds_all[p][(wid + 4 * i) * 512]);
      gp[i] += 512;
    }
  }

  for (int ks = 0; ks < 32; ++ks) {
    if (ks < 31) asm volatile("s_waitcnt vmcnt(9)" ::: "memory");
    else         asm volatile("s_waitcnt vmcnt(0)" ::: "memory");
    __builtin_amdgcn_s_barrier();
    SCHED_FENCE();
    if (ks < 30) {
      const int nb = (ks + 2) % 3;
#pragma unroll
      for (int i = 0; i < 9; ++i) {
        gload_lds16(gp[i], &lds_all[nb][(wid + 4 * i) * 512]);
        gp[i] += 512;
      }
    }
    const int cur = ks % 3;
    short8 b0[2], b1[2], b2[2];
#pragma unroll
    for (int c = 0; c < 2; ++c) {
      const int cf = wcol * 2 + c;
      b0[c] = *(const short8*)&lds_all[cur][(24 + 0 * 4 + cf) * 512 + lane * 8];
      b1[c] = *(const short8*)&lds_all[cur][(24 + 1 * 4 + cf) * 512 + lane * 8];
      b2[c] = *(const short8*)&lds_all[cur][(24 + 2 * 4 + cf) * 512 + lane * 8];
    }
#pragma unroll
    for (int r = 0; r < 4; ++r) {
      const int rf = wrow * 4 + r;
      short8 a0 = *(const short8*)&lds_all[cur][(0 * 8 + rf) * 512 + lane * 8];
      short8 a1 = *(const short8*)&lds_all[cur][(1 * 8 + rf) * 512 + lane * 8];
      short8 a2 = *(const short8*)&lds_all[cur][(2 * 8 + rf) * 512 + lane * 8];
#pragma unroll
      for (int c = 0; c < 2; ++c) {
        f32x4 dd = acc[r][c];
        dd = mfma16(a0, b0[c], dd);
        dd = mfma16(a0, b1[c], dd);
        dd = mfma16(a1, b0[c], dd);
        dd = mfma16(a1, b1[c], dd);
        dd = mfma16(a0, b2[c], dd);
        dd = mfma16(a2, b0[c], dd);
        acc[r][c] = dd;
      }
    }
  }
  float* P = part + (size_t)kz * BATCH * NCD;
#pragma unroll
  for (int r = 0; r < 4; ++r)
#pragma unroll
    for (int c = 0; c < 2; ++c) {
      int row = bm + wrow * 64 + r * 16 + (lane >> 4) * 4;
      int col = bn_t * 64 + wcol * 32 + c * 16 + (lane & 15);
#pragma unroll
      for (int i = 0; i < 4; ++i)
        P[(size_t)(row + i) * NCD + col] = acc[r][c][i];
    }
}

// ---------------------------------------------------------------------------
__global__ __launch_bounds__(256) void k_reduce_bias(
    const float* __restrict__ part, const float* __restrict__ bias,
    float* __restrict__ e) {
  size_t o = ((size_t)blockIdx.x * 256 + threadIdx.x) * 4;
  int n = (int)(o & (NCD - 1));
  f32x4 s = *(const f32x4*)(part + o);
  s += *(const f32x4*)(part + (size_t)1 * BATCH * NCD + o);
  s += *(const f32x4*)(part + (size_t)2 * BATCH * NCD + o);
  s += *(const f32x4*)(part + (size_t)3 * BATCH * NCD + o);
  s += *(const f32x4*)(bias + n);
  *(f32x4*)(e + o) = s;
}

// ---------------------------------------------------------------------------
// k3_gemm: triple-buffered counted-vmcnt pipeline (validated round 14).
// ---------------------------------------------------------------------------
__global__ __launch_bounds__(512) void k3_gemm(
    const u16* __restrict__ Ab, const u16* __restrict__ Bb,
    const float* __restrict__ bias, float* __restrict__ C) {
  __shared__ u16 As[3][4][64][8];
  __shared__ u16 Bs[3][8][64][8];
  const int t = threadIdx.x;
  const int wid = t >> 6, lane = t & 63;
  const int wrow = wid >> 2, wcol = wid & 3;
  const int d = blockIdx.x + (blockIdx.y << 3);
  const int xcd = d & 7, sl = d >> 3;            // sl 0..31
  const int bn = ((xcd << 2) + (sl >> 3)) * 128; // 32 panels, 4 per XCD
  const int bm = (sl & 7) * 64;

  const size_t gbB = ((size_t)(bn >> 4) + wid) * 64;
  const size_t gaA = ((size_t)(bm >> 4) + wid) * 64;

  f32x4 acc[2][2];
#pragma unroll
  for (int r = 0; r < 2; ++r)
#pragma unroll
    for (int c = 0; c < 2; ++c) acc[r][c] = (f32x4)0.f;

#pragma unroll
  for (int p = 0; p < 2; ++p) {
    gload_lds16(Bb + (gbB + p) * 512 + lane * 8, &Bs[p][wid][0][0]);
    if (wid < 4)
      gload_lds16(Ab + (gaA + p) * 512 + lane * 8, &As[p][wid][0][0]);
  }

  for (int ks = 0; ks < 64; ++ks) {
    if (ks < 63) {
      if (wid < 4) asm volatile("s_waitcnt vmcnt(2)" ::: "memory");
      else         asm volatile("s_waitcnt vmcnt(1)" ::: "memory");
    } else {
      asm volatile("s_waitcnt vmcnt(0)" ::: "memory");
    }
    __builtin_amdgcn_s_barrier();
    SCHED_FENCE();
    if (ks < 62) {
      const int nb = (ks + 2) % 3;
      gload_lds16(Bb + (gbB + ks + 2) * 512 + lane * 8, &Bs[nb][wid][0][0]);
      if (wid < 4)
        gload_lds16(Ab + (gaA + ks + 2) * 512 + lane * 8, &As[nb][wid][0][0]);
    }
    const int cur = ks % 3;
    short8 a[2], b[2];
#pragma unroll
    for (int r = 0; r < 2; ++r) a[r] = *(const short8*)&As[cur][wrow * 2 + r][lane][0];
#pragma unroll
    for (int c = 0; c < 2; ++c) b[c] = *(const short8*)&Bs[cur][wcol * 2 + c][lane][0];
#pragma unroll
    for (int r = 0; r < 2; ++r)
#pragma unroll
      for (int c = 0; c < 2; ++c) acc[r][c] = mfma16(a[r], b[c], acc[r][c]);
  }
#pragma unroll
  for (int r = 0; r < 2; ++r)
#pragma unroll
    for (int c = 0; c < 2; ++c) {
      int row = bm + wrow * 32 + r * 16 + (lane >> 4) * 4;
      int col = bn + wcol * 32 + c * 16 + (lane & 15);
      float bb = bias[col];
#pragma unroll
      for (int i = 0; i < 4; ++i)
        C[(size_t)(row + i) * HID + col] = acc[r][c][i] + bb;
    }
}

// ---------------------------------------------------------------------------
// k_cost (MFMA): 6-term bf16x3 over K=64 (unchanged).
// ---------------------------------------------------------------------------
__global__ __launch_bounds__(512) void k_cost(
    const float* __restrict__ e_glob,     // [16384][64]
    const float* __restrict__ codebook,   // [1024][64]
    float* __restrict__ cost) {           // [16384][1024]
  __shared__ u16 Ea[2][3][8][64][8];
  __shared__ u16 Cbs[2][3][8][64][8];
  __shared__ float enorm[128], cnorm[128];
  const int t = threadIdx.x;
  const int wid = t >> 6, lane = t & 63;
  const int wrow = wid >> 2, wcol = wid & 3;
  const int r0 = blockIdx.x * 128;
  const int c0 = blockIdx.y * 128;

  {
    const int fr = lane & 15, kc = lane >> 4;
    const float* ea = e_glob   + (size_t)(r0 + wid * 16 + fr) * CD + kc * 8;
    const float* cb = codebook + (size_t)(c0 + wid * 16 + fr) * CD + kc * 8;
#pragma unroll
    for (int ks = 0; ks < 2; ++ks) {
      float va[8], vb[8];
      *(f32x4*)&va[0] = *(const f32x4*)(ea + ks * 32);
      *(f32x4*)&va[4] = *(const f32x4*)(ea + ks * 32 + 4);
      *(f32x4*)&vb[0] = *(const f32x4*)(cb + ks * 32);
      *(f32x4*)&vb[4] = *(const f32x4*)(cb + ks * 32 + 4);
      H8 a1, a2, a3, b1, b2, b3;
#pragma unroll
      for (int i = 0; i < 8; ++i) {
        split3(va[i], a1.h[i], a2.h[i], a3.h[i]);
        split3(vb[i], b1.h[i], b2.h[i], b3.h[i]);
      }
      *(short8*)&Ea[ks][0][wid][lane][0] = a1.v;
      *(short8*)&Ea[ks][1][wid][lane][0] = a2.v;
      *(short8*)&Ea[ks][2][wid][lane][0] = a3.v;
      *(short8*)&Cbs[ks][0][wid][lane][0] = b1.v;
      *(short8*)&Cbs[ks][1][wid][lane][0] = b2.v;
      *(short8*)&Cbs[ks][2][wid][lane][0] = b3.v;
    }
  }
  if (t < 256) {
    const int which = t >> 7, idx = t & 127;
    const float* p = which ? codebook + (size_t)(c0 + idx) * CD
                           : e_glob   + (size_t)(r0 + idx) * CD;
    float s = 0.f;
#pragma unroll
    for (int k = 0; k < 16; ++k) {
      f32x4 v = *(const f32x4*)(p + k * 4);
      s += v.x * v.x + v.y * v.y + v.z * v.z + v.w * v.w;
    }
    if (which) cnorm[idx] = s; else enorm[idx] = s;
  }
  __syncthreads();

  f32x4 acc[4][2];
#pragma unroll
  for (int r = 0; r < 4; ++r)
#pragma unroll
    for (int c = 0; c < 2; ++c) acc[r][c] = (f32x4)0.f;
#pragma unroll
  for (int ks = 0; ks < 2; ++ks) {
    short8 a0[4], a1[4], a2[4], b0[2], b1[2], b2[2];
#pragma unroll
    for (int r = 0; r < 4; ++r) {
      a0[r] = *(const short8*)&Ea[ks][0][wrow * 4 + r][lane][0];
      a1[r] = *(const short8*)&Ea[ks][1][wrow * 4 + r][lane][0];
      a2[r] = *(const short8*)&Ea[ks][2][wrow * 4 + r][lane][0];
    }
#pragma unroll
    for (int c = 0; c < 2; ++c) {
      b0[c] = *(const short8*)&Cbs[ks][0][wcol * 2 + c][lane][0];
      b1[c] = *(const short8*)&Cbs[ks][1][wcol * 2 + c][lane][0];
      b2[c] = *(const short8*)&Cbs[ks][2][wcol * 2 + c][lane][0];
    }
#pragma unroll
    for (int r = 0; r < 4; ++r)
#pragma unroll
      for (int c = 0; c < 2; ++c) {
        f32x4 dd = acc[r][c];
        dd = mfma16(a0[r], b0[c], dd);
        dd = mfma16(a0[r], b1[c], dd);
        dd = mfma16(a1[r], b0[c], dd);
        dd = mfma16(a1[r], b1[c], dd);
        dd = mfma16(a0[r], b2[c], dd);
        dd = mfma16(a2[r], b0[c], dd);
        acc[r][c] = dd;
      }
  }
#pragma unroll
  for (int r = 0; r < 4; ++r)
#pragma unroll
    for (int c = 0; c < 2; ++c) {
      const int rl = wrow * 64 + r * 16 + (lane >> 4) * 4;
      const int cl = wcol * 32 + c * 16 + (lane & 15);
      const float cn = cnorm[cl];
#pragma unroll
      for (int i = 0; i < 4; ++i) {
        float d2 = enorm[rl + i] + cn - 2.f * acc[r][c][i];
        cost[(size_t)(r0 + rl + i) * CB + c0 + cl] = sqrtf(fmaxf(d2, 0.f));
      }
    }
}

// ---------------------------------------------------------------------------
// k_assign: one wave per sample, all-register JV with DPP reduce (unchanged).
// ---------------------------------------------------------------------------
__global__ __launch_bounds__(64, 1) void k_assign(
    const float* __restrict__ cost_g, const float* __restrict__ codebook,
    float* __restrict__ q_out, float* __restrict__ idx_out) {
  __shared__ int idxl[32];
  const int lane = threadIdx.x;
  const int s = blockIdx.x;
  const float* __restrict__ cost = cost_g + (size_t)s * NC * CB;

  double v_[16], minv_[16];
  u32 wp_[16];                        // low16 = way, high16 = pm
  double u_val = 0.0;                 // lane l holds u[l] (rows 1..32)
#pragma unroll
  for (int r = 0; r < 16; ++r) { v_[r] = 0.0; wp_[r] = 0; }

  float pf[16];
#pragma unroll
  for (int r = 0; r < 16; ++r) pf[r] = cost[r * 64 + lane];   // row 0

  for (int i = 1; i <= NC; ++i) {
#pragma unroll
    for (int r = 0; r < 16; ++r) minv_[r] = 1e300;
    u32 col_used = 0;
    unsigned long long rowmask = 0ull;
    int j0 = 0;
    int i0 = i;
    float cc[16];
#pragma unroll
    for (int r = 0; r < 16; ++r) cc[r] = pf[r];
    int first = 1;
    for (int guard = 0; guard < 1056; ++guard) {
      rowmask |= (1ull << i0);
      const double ui0 = __shfl(u_val, i0);
      if (first && i < NC) {
#pragma unroll
        for (int r = 0; r < 16; ++r)
          pf[r] = cost[(size_t)i * CB + r * 64 + lane];
      }
      first = 0;
      double bv = 1e301; int bj = 1 << 20;
#pragma unroll
      for (int r = 0; r < 16; ++r) {
        const int j = 1 + lane + r * 64;
        if (!((col_used >> r) & 1u)) {
          double cur = (double)cc[r] - ui0 - v_[r];
          if (cur < minv_[r]) { minv_[r] = cur; wp_[r] = (wp_[r] & 0xFFFF0000u) | (u32)j0; }
          if (minv_[r] < bv) { bv = minv_[r]; bj = j; }
        }
      }
      { double ov = dpp_f64<0xB1>(bv);  int oj = dpp_i32<0xB1>(bj);
        if (ov < bv || (ov == bv && oj < bj)) { bv = ov; bj = oj; } }
      { double ov = dpp_f64<0x4E>(bv);  int oj = dpp_i32<0x4E>(bj);
        if (ov < bv || (ov == bv && oj < bj)) { bv = ov; bj = oj; } }
      { double ov = dpp_f64<0x124>(bv); int oj = dpp_i32<0x124>(bj);
        if (ov < bv || (ov == bv && oj < bj)) { bv = ov; bj = oj; } }
      { double ov = dpp_f64<0x128>(bv); int oj = dpp_i32<0x128>(bj);
        if (ov < bv || (ov == bv && oj < bj)) { bv = ov; bj = oj; } }
#pragma unroll
      for (int off = 16; off < 64; off <<= 1) {
        double ov = __shfl_xor(bv, off);
        int oj = __shfl_xor(bj, off);
        if (ov < bv || (ov == bv && oj < bj)) { bv = ov; bj = oj; }
      }
      const double delta = bv;
      const int k = bj;
      const int rk = (k - 1) >> 6, kl = (k - 1) & 63;
      u32 sel = 0;
#pragma unroll
      for (int r = 0; r < 16; ++r) if (r == rk) sel = wp_[r];
      const int pmk = ((u32)__shfl((int)sel, kl)) >> 16;
      float ccn[16];
      if (pmk > 0) {
        const float* crow = cost + (size_t)(pmk - 1) * CB;
#pragma unroll
        for (int r = 0; r < 16; ++r) ccn[r] = crow[r * 64 + lane];
      }
      if ((rowmask >> lane) & 1ull) u_val += delta;
#pragma unroll
      for (int r = 0; r < 16; ++r) {
        const int j = 1 + lane + r * 64;
        if ((col_used >> r) & 1u) v_[r] -= delta;
        else {
          minv_[r] -= delta;
          if (j == k) col_used |= (1u << r);
        }
      }
      j0 = k;
      if (pmk == 0) break;
      i0 = pmk;
#pragma unroll
      for (int r = 0; r < 16; ++r) cc[r] = ccn[r];
    }
    int jj = j0;
    while (jj != 0) {
      const int rj = (jj - 1) >> 6, lj = (jj - 1) & 63;
      u32 wsel = 0;
#pragma unroll
      for (int r = 0; r < 16; ++r) if (r == rj) wsel = wp_[r];
      const int j1 = ((u32)__shfl((int)wsel, lj)) & 0xFFFFu;
      int newpm;
      if (j1 == 0) newpm = i;
      else {
        const int r1 = (j1 - 1) >> 6, l1 = (j1 - 1) & 63;
        u32 psel = 0;
#pragma unroll
        for (int r = 0; r < 16; ++r) if (r == r1) psel = wp_[r];
        newpm = ((u32)__shfl((int)psel, l1)) >> 16;
      }
#pragma unroll
      for (int r = 0; r < 16; ++r)
        if (lane == lj && r == rj) wp_[r] = (wp_[r] & 0xFFFFu) | ((u32)newpm << 16);
      jj = j1;
    }
  }

#pragma unroll
  for (int r = 0; r < 16; ++r) {
    const u32 pm = wp_[r] >> 16;
    if (pm > 0) idxl[pm - 1] = lane + r * 64;
  }
  WAVE_SYNC(); SCHED_FENCE();
  if (lane < NC) idx_out[(size_t)s * NC + lane] = (float)idxl[lane];
#pragma unroll
  for (int p = 0; p < 8; ++p) {
    int vi = p * 64 + lane;
    int r = vi >> 4, c4 = vi & 15;
    int ci = idxl[r];
    float4 qv = *(const float4*)&codebook[(size_t)ci * 64 + c4 * 4];
    *(float4*)&q_out[(size_t)s * NCD + r * 64 + c4 * 4] = qv;
  }
}

// ---------------------------------------------------------------------------
extern "C" void kernel_launch(void* const* d_in, const int* in_sizes, int n_in,
                              void* d_out, int out_size, void* d_ws, size_t ws_size,
                              hipStream_t stream) {
  (void)in_sizes; (void)n_in; (void)out_size; (void)ws_size;
  const float* x        = (const float*)d_in[0];
  const float* codebook = (const float*)d_in[1];
  const float* enc_w    = (const float*)d_in[2];
  const float* enc_b    = (const float*)d_in[3];
  const float* dec_w    = (const float*)d_in[4];
  const float* dec_b    = (const float*)d_in[5];

  float* out = (float*)d_out;
  float* r_out   = out;                       // [512][4096]
  float* q_out   = out + 2097152;             // [512][32][64]
  float* e_out   = out + 2097152 + 1048576;   // [512][32][64]
  float* idx_out = out + 2097152 + 2097152;   // [512][32] as float

  // ws layout (64 MB, phase-disjoint):
  //  phase 1: enc_w blobs [0,48M), k1 partials [48M,64M)
  //           x blobs (12M) in dead d_out regions: r_out (A1,A2), q_out (A3)
  //  phase 2: cost [0,64M)
  //  phase 3: q blob [0,2M), dec_w blob [2M,18M)
  char* ws = (char*)d_ws;
  u16* B1 = (u16*)ws;
  u16* B2 = (u16*)(ws + (16u << 20));
  u16* B3 = (u16*)(ws + (32u << 20));
  float* part = (float*)(ws + (48u << 20));
  float* cost_ws = (float*)ws;
  u16* qb  = (u16*)ws;
  u16* dwb = (u16*)(ws + (2u << 20));
  u16* A1 = (u16*)r_out;               // [0,4M) of r
  u16* A2 = (u16*)r_out + 2097152;     // [4M,8M) of r
  u16* A3 = (u16*)q_out;               // q region (4 MB exactly)

  conv_split3<HID><<<1024, 256, 0, stream>>>(x, A1, A2, A3);
  conv_split3<HID><<<4096, 256, 0, stream>>>(enc_w, B1, B2, B3);
  k1_gemm<<<dim3(4, 32, 4), 256, 0, stream>>>(A1, A2, A3, B1, B2, B3, part);
  k_reduce_bias<<<1024, 256, 0, stream>>>(part, enc_b, e_out);
  k_cost<<<dim3(128, 8), 512, 0, stream>>>(e_out, codebook, cost_ws);
  k_assign<<<BATCH, 64, 0, stream>>>(cost_ws, codebook, q_out, idx_out);
  conv_split1_dual<<<4608, 256, 0, stream>>>(dec_w, dwb, q_out, qb);
  k3_gemm<<<dim3(8, 32), 512, 0, stream>>>(qb, dwb, dec_b, r_out);
}

// Round 16
// 208.732 us; speedup vs baseline: 1.0472x; 1.0472x over previous
//
#include <hip/hip_runtime.h>
#include <hip/hip_bf16.h>
#include <stdint.h>

// Sizes
#define BATCH 512
#define HID   4096
#define NC    32
#define CD    64
#define CB    1024
#define NCD   2048   // NC*CD

typedef unsigned short u16;
typedef unsigned int   u32;
typedef unsigned long long u64;
typedef __attribute__((ext_vector_type(8))) short short8;  // 8 bf16
typedef __attribute__((ext_vector_type(4))) float f32x4;

#define WAVE_SYNC()  asm volatile("s_waitcnt lgkmcnt(0)" ::: "memory")
#define SCHED_FENCE() __builtin_amdgcn_sched_barrier(0)

__device__ inline u16 bf16_rne(float f) {
  u32 u = __builtin_bit_cast(u32, f);
  u32 r = u + 0x7FFFu + ((u >> 16) & 1u);
  return (u16)(r >> 16);
}
__device__ inline float bf16_f32(u16 h) {
  u32 u = ((u32)h) << 16;
  return __builtin_bit_cast(float, u);
}
__device__ inline void split3(float a, u16& h1, u16& h2, u16& h3) {
  h1 = bf16_rne(a);
  float r1 = a - bf16_f32(h1);
  h2 = bf16_rne(r1);
  float r2 = r1 - bf16_f32(h2);
  h3 = bf16_rne(r2);
}
__device__ inline f32x4 mfma16(short8 a, short8 b, f32x4 c) {
  return __builtin_amdgcn_mfma_f32_16x16x32_bf16(a, b, c, 0, 0, 0);
}
__device__ inline void gload_lds16(const u16* g, u16* l) {
  __builtin_amdgcn_global_load_lds(
      (const __attribute__((address_space(1))) u32*)(const void*)g,
      (__attribute__((address_space(3))) u32*)(void*)l, 16, 0, 0);
}

// DPP cross-lane movers (plain-VALU latency, no LDS round trip).
template<int CTRL>
__device__ inline double dpp_f64(double x) {
  u64 u = __builtin_bit_cast(u64, x);
  int lo = (int)(u32)u, hi = (int)(u32)(u >> 32);
  lo = __builtin_amdgcn_update_dpp(lo, lo, CTRL, 0xF, 0xF, true);
  hi = __builtin_amdgcn_update_dpp(hi, hi, CTRL, 0xF, 0xF, true);
  u64 r = ((u64)(u32)hi << 32) | (u64)(u32)lo;
  return __builtin_bit_cast(double, r);
}
template<int CTRL>
__device__ inline int dpp_i32(int x) {
  return __builtin_amdgcn_update_dpp(x, x, CTRL, 0xF, 0xF, true);
}

union H8 { u16 h[8]; short8 v; };

// ---------------------------------------------------------------------------
// conv_split3: f32 [ROWS][K] -> 3 bf16 fragment-blob arrays (coalesced read).
// ---------------------------------------------------------------------------
template<int K>
__global__ __launch_bounds__(256) void conv_split3(
    const float* __restrict__ src, u16* __restrict__ d1,
    u16* __restrict__ d2, u16* __restrict__ d3) {
  __shared__ float st[4][16][36];
  const int t = threadIdx.x;
  const int wv = t >> 6, l = t & 63;
  const int g = blockIdx.x * 4 + wv;
  const int rowbase = (g / (K / 32)) * 16;
  const int kbase   = (g % (K / 32)) * 32;
  {
    const float* s = src + (size_t)(rowbase + (l >> 2)) * K + kbase + (l & 3) * 8;
    *(f32x4*)&st[wv][l >> 2][(l & 3) * 8]     = *(const f32x4*)s;
    *(f32x4*)&st[wv][l >> 2][(l & 3) * 8 + 4] = *(const f32x4*)(s + 4);
  }
  __syncthreads();
  float vv[8];
  *(f32x4*)&vv[0] = *(const f32x4*)&st[wv][l & 15][(l >> 4) * 8];
  *(f32x4*)&vv[4] = *(const f32x4*)&st[wv][l & 15][(l >> 4) * 8 + 4];
  H8 o1, o2, o3;
#pragma unroll
  for (int i = 0; i < 8; ++i) split3(vv[i], o1.h[i], o2.h[i], o3.h[i]);
  size_t off = (size_t)g * 512 + l * 8;
  *(short8*)(d1 + off) = o1.v;
  *(short8*)(d2 + off) = o2.v;
  *(short8*)(d3 + off) = o3.v;
}

// ---------------------------------------------------------------------------
// conv_split1_dual: two f32 sources -> bf16 blobs in one launch (K=2048 both).
// ---------------------------------------------------------------------------
__global__ __launch_bounds__(256) void conv_split1_dual(
    const float* __restrict__ s1, u16* __restrict__ dst1,
    const float* __restrict__ s2, u16* __restrict__ dst2) {
  __shared__ float st[4][16][36];
  const int t = threadIdx.x;
  const int wv = t >> 6, l = t & 63;
  const int bb = blockIdx.x;
  const float* src; u16* dst; int g;
  if (bb < 4096) { src = s1; dst = dst1; g = bb * 4 + wv; }
  else           { src = s2; dst = dst2; g = (bb - 4096) * 4 + wv; }
  const int rowbase = (g / 64) * 16;     // K/32 = 64
  const int kbase   = (g % 64) * 32;
  {
    const float* s = src + (size_t)(rowbase + (l >> 2)) * 2048 + kbase + (l & 3) * 8;
    *(f32x4*)&st[wv][l >> 2][(l & 3) * 8]     = *(const f32x4*)s;
    *(f32x4*)&st[wv][l >> 2][(l & 3) * 8 + 4] = *(const f32x4*)(s + 4);
  }
  __syncthreads();
  float vv[8];
  *(f32x4*)&vv[0] = *(const f32x4*)&st[wv][l & 15][(l >> 4) * 8];
  *(f32x4*)&vv[4] = *(const f32x4*)&st[wv][l & 15][(l >> 4) * 8 + 4];
  H8 o1;
#pragma unroll
  for (int i = 0; i < 8; ++i) o1.h[i] = bf16_rne(vv[i]);
  *(short8*)(dst + (size_t)g * 512 + l * 8) = o1.v;
}

// ---------------------------------------------------------------------------
// k1_gemm (round 16 = round 13/14 structure + setprio): pure-blob bf16x3
// 6-term GEMM, 128x64 tile, split-K=4, grid 512 -> 2 blocks/CU, 72 KiB dbuf,
// single barrier per K-step. s_setprio(1) wraps the MFMA cluster (T5): the
// 2 co-resident blocks are at different phases, so the scheduler can favor
// the MFMA-issuing block. K/MFMA order bit-identical to rounds 8-15.
// ---------------------------------------------------------------------------
__global__ __launch_bounds__(256, 2) void k1_gemm(
    const u16* __restrict__ A1, const u16* __restrict__ A2,
    const u16* __restrict__ A3,
    const u16* __restrict__ B1, const u16* __restrict__ B2,
    const u16* __restrict__ B3, float* __restrict__ part) {
  __shared__ u16 lds_all[2][36 * 512];
  const int t = threadIdx.x;
  const int wid = t >> 6, lane = t & 63;      // 4 waves
  const int wrow = wid >> 1, wcol = wid & 1;  // 2x2 wave grid
  const int d = blockIdx.x + (blockIdx.y << 2) + (blockIdx.z << 7);  // 0..511
  const int xcd = d & 7, sl = d >> 3;            // sl 0..63
  const int panel = (xcd << 4) + (sl >> 2);      // 0..127
  const int bm = (sl & 3) * 128;
  const int bn_t = panel & 31;                   // 64-col tile id
  const int kz = panel >> 5;                     // 0..3
  const int ks0 = kz * 32;                       // 32 ksteps per kz

  const u16* gp[9];
#pragma unroll
  for (int i = 0; i < 9; ++i) {
    const int b = wid + 4 * i;
    const u16* base;
    size_t frag;
    if (b < 24) {
      const int s = b >> 3, rf = b & 7;
      base = (s == 0) ? A1 : (s == 1) ? A2 : A3;
      frag = (size_t)((bm >> 4) + rf);
    } else {
      const int bb = b - 24;
      const int s = bb >> 2, cf = bb & 3;
      base = (s == 0) ? B1 : (s == 1) ? B2 : B3;
      frag = (size_t)(bn_t * 4 + cf);
    }
    gp[i] = base + (frag * 128 + ks0) * 512 + lane * 8;
  }

  f32x4 acc[4][2];
#pragma unroll
  for (int r = 0; r < 4; ++r)
#pragma unroll
    for (int c = 0; c < 2; ++c) acc[r][c] = (f32x4)0.f;

#pragma unroll
  for (int i = 0; i < 9; ++i) {
    gload_lds16(gp[i], &lds_all[0][(wid + 4 * i) * 512]);
    gp[i] += 512;
  }
  __syncthreads();

  for (int ks = 0; ks < 32; ++ks) {
    const int cur = ks & 1, nxt = cur ^ 1;
    if (ks < 31) {
#pragma unroll
      for (int i = 0; i < 9; ++i) {
        gload_lds16(gp[i], &lds_all[nxt][(wid + 4 * i) * 512]);
        gp[i] += 512;
      }
    }
    short8 b0[2], b1[2], b2[2];
#pragma unroll
    for (int c = 0; c < 2; ++c) {
      const int cf = wcol * 2 + c;
      b0[c] = *(const short8*)&lds_all[cur][(24 + 0 * 4 + cf) * 512 + lane * 8];
      b1[c] = *(const short8*)&lds_all[cur][(24 + 1 * 4 + cf) * 512 + lane * 8];
      b2[c] = *(const short8*)&lds_all[cur][(24 + 2 * 4 + cf) * 512 + lane * 8];
    }
    __builtin_amdgcn_s_setprio(1);
#pragma unroll
    for (int r = 0; r < 4; ++r) {
      const int rf = wrow * 4 + r;
      short8 a0 = *(const short8*)&lds_all[cur][(0 * 8 + rf) * 512 + lane * 8];
      short8 a1 = *(const short8*)&lds_all[cur][(1 * 8 + rf) * 512 + lane * 8];
      short8 a2 = *(const short8*)&lds_all[cur][(2 * 8 + rf) * 512 + lane * 8];
#pragma unroll
      for (int c = 0; c < 2; ++c) {
        f32x4 dd = acc[r][c];
        dd = mfma16(a0, b0[c], dd);
        dd = mfma16(a0, b1[c], dd);
        dd = mfma16(a1, b0[c], dd);
        dd = mfma16(a1, b1[c], dd);
        dd = mfma16(a0, b2[c], dd);
        dd = mfma16(a2, b0[c], dd);
        acc[r][c] = dd;
      }
    }
    __builtin_amdgcn_s_setprio(0);
    __syncthreads();
  }
  float* P = part + (size_t)kz * BATCH * NCD;
#pragma unroll
  for (int r = 0; r < 4; ++r)
#pragma unroll
    for (int c = 0; c < 2; ++c) {
      int row = bm + wrow * 64 + r * 16 + (lane >> 4) * 4;
      int col = bn_t * 64 + wcol * 32 + c * 16 + (lane & 15);
#pragma unroll
      for (int i = 0; i < 4; ++i)
        P[(size_t)(row + i) * NCD + col] = acc[r][c][i];
    }
}

// ---------------------------------------------------------------------------
__global__ __launch_bounds__(256) void k_reduce_bias(
    const float* __restrict__ part, const float* __restrict__ bias,
    float* __restrict__ e) {
  size_t o = ((size_t)blockIdx.x * 256 + threadIdx.x) * 4;
  int n = (int)(o & (NCD - 1));
  f32x4 s = *(const f32x4*)(part + o);
  s += *(const f32x4*)(part + (size_t)1 * BATCH * NCD + o);
  s += *(const f32x4*)(part + (size_t)2 * BATCH * NCD + o);
  s += *(const f32x4*)(part + (size_t)3 * BATCH * NCD + o);
  s += *(const f32x4*)(bias + n);
  *(f32x4*)(e + o) = s;
}

// ---------------------------------------------------------------------------
// k3_gemm: triple-buffered counted-vmcnt pipeline (validated round 14).
// ---------------------------------------------------------------------------
__global__ __launch_bounds__(512) void k3_gemm(
    const u16* __restrict__ Ab, const u16* __restrict__ Bb,
    const float* __restrict__ bias, float* __restrict__ C) {
  __shared__ u16 As[3][4][64][8];
  __shared__ u16 Bs[3][8][64][8];
  const int t = threadIdx.x;
  const int wid = t >> 6, lane = t & 63;
  const int wrow = wid >> 2, wcol = wid & 3;
  const int d = blockIdx.x + (blockIdx.y << 3);
  const int xcd = d & 7, sl = d >> 3;            // sl 0..31
  const int bn = ((xcd << 2) + (sl >> 3)) * 128; // 32 panels, 4 per XCD
  const int bm = (sl & 7) * 64;

  const size_t gbB = ((size_t)(bn >> 4) + wid) * 64;
  const size_t gaA = ((size_t)(bm >> 4) + wid) * 64;

  f32x4 acc[2][2];
#pragma unroll
  for (int r = 0; r < 2; ++r)
#pragma unroll
    for (int c = 0; c < 2; ++c) acc[r][c] = (f32x4)0.f;

#pragma unroll
  for (int p = 0; p < 2; ++p) {
    gload_lds16(Bb + (gbB + p) * 512 + lane * 8, &Bs[p][wid][0][0]);
    if (wid < 4)
      gload_lds16(Ab + (gaA + p) * 512 + lane * 8, &As[p][wid][0][0]);
  }

  for (int ks = 0; ks < 64; ++ks) {
    if (ks < 63) {
      if (wid < 4) asm volatile("s_waitcnt vmcnt(2)" ::: "memory");
      else         asm volatile("s_waitcnt vmcnt(1)" ::: "memory");
    } else {
      asm volatile("s_waitcnt vmcnt(0)" ::: "memory");
    }
    __builtin_amdgcn_s_barrier();
    SCHED_FENCE();
    if (ks < 62) {
      const int nb = (ks + 2) % 3;
      gload_lds16(Bb + (gbB + ks + 2) * 512 + lane * 8, &Bs[nb][wid][0][0]);
      if (wid < 4)
        gload_lds16(Ab + (gaA + ks + 2) * 512 + lane * 8, &As[nb][wid][0][0]);
    }
    const int cur = ks % 3;
    short8 a[2], b[2];
#pragma unroll
    for (int r = 0; r < 2; ++r) a[r] = *(const short8*)&As[cur][wrow * 2 + r][lane][0];
#pragma unroll
    for (int c = 0; c < 2; ++c) b[c] = *(const short8*)&Bs[cur][wcol * 2 + c][lane][0];
#pragma unroll
    for (int r = 0; r < 2; ++r)
#pragma unroll
      for (int c = 0; c < 2; ++c) acc[r][c] = mfma16(a[r], b[c], acc[r][c]);
  }
#pragma unroll
  for (int r = 0; r < 2; ++r)
#pragma unroll
    for (int c = 0; c < 2; ++c) {
      int row = bm + wrow * 32 + r * 16 + (lane >> 4) * 4;
      int col = bn + wcol * 32 + c * 16 + (lane & 15);
      float bb = bias[col];
#pragma unroll
      for (int i = 0; i < 4; ++i)
        C[(size_t)(row + i) * HID + col] = acc[r][c][i] + bb;
    }
}

// ---------------------------------------------------------------------------
// k_cost (MFMA): 6-term bf16x3 over K=64 (unchanged).
// ---------------------------------------------------------------------------
__global__ __launch_bounds__(512) void k_cost(
    const float* __restrict__ e_glob,     // [16384][64]
    const float* __restrict__ codebook,   // [1024][64]
    float* __restrict__ cost) {           // [16384][1024]
  __shared__ u16 Ea[2][3][8][64][8];
  __shared__ u16 Cbs[2][3][8][64][8];
  __shared__ float enorm[128], cnorm[128];
  const int t = threadIdx.x;
  const int wid = t >> 6, lane = t & 63;
  const int wrow = wid >> 2, wcol = wid & 3;
  const int r0 = blockIdx.x * 128;
  const int c0 = blockIdx.y * 128;

  {
    const int fr = lane & 15, kc = lane >> 4;
    const float* ea = e_glob   + (size_t)(r0 + wid * 16 + fr) * CD + kc * 8;
    const float* cb = codebook + (size_t)(c0 + wid * 16 + fr) * CD + kc * 8;
#pragma unroll
    for (int ks = 0; ks < 2; ++ks) {
      float va[8], vb[8];
      *(f32x4*)&va[0] = *(const f32x4*)(ea + ks * 32);
      *(f32x4*)&va[4] = *(const f32x4*)(ea + ks * 32 + 4);
      *(f32x4*)&vb[0] = *(const f32x4*)(cb + ks * 32);
      *(f32x4*)&vb[4] = *(const f32x4*)(cb + ks * 32 + 4);
      H8 a1, a2, a3, b1, b2, b3;
#pragma unroll
      for (int i = 0; i < 8; ++i) {
        split3(va[i], a1.h[i], a2.h[i], a3.h[i]);
        split3(vb[i], b1.h[i], b2.h[i], b3.h[i]);
      }
      *(short8*)&Ea[ks][0][wid][lane][0] = a1.v;
      *(short8*)&Ea[ks][1][wid][lane][0] = a2.v;
      *(short8*)&Ea[ks][2][wid][lane][0] = a3.v;
      *(short8*)&Cbs[ks][0][wid][lane][0] = b1.v;
      *(short8*)&Cbs[ks][1][wid][lane][0] = b2.v;
      *(short8*)&Cbs[ks][2][wid][lane][0] = b3.v;
    }
  }
  if (t < 256) {
    const int which = t >> 7, idx = t & 127;
    const float* p = which ? codebook + (size_t)(c0 + idx) * CD
                           : e_glob   + (size_t)(r0 + idx) * CD;
    float s = 0.f;
#pragma unroll
    for (int k = 0; k < 16; ++k) {
      f32x4 v = *(const f32x4*)(p + k * 4);
      s += v.x * v.x + v.y * v.y + v.z * v.z + v.w * v.w;
    }
    if (which) cnorm[idx] = s; else enorm[idx] = s;
  }
  __syncthreads();

  f32x4 acc[4][2];
#pragma unroll
  for (int r = 0; r < 4; ++r)
#pragma unroll
    for (int c = 0; c < 2; ++c) acc[r][c] = (f32x4)0.f;
#pragma unroll
  for (int ks = 0; ks < 2; ++ks) {
    short8 a0[4], a1[4], a2[4], b0[2], b1[2], b2[2];
#pragma unroll
    for (int r = 0; r < 4; ++r) {
      a0[r] = *(const short8*)&Ea[ks][0][wrow * 4 + r][lane][0];
      a1[r] = *(const short8*)&Ea[ks][1][wrow * 4 + r][lane][0];
      a2[r] = *(const short8*)&Ea[ks][2][wrow * 4 + r][lane][0];
    }
#pragma unroll
    for (int c = 0; c < 2; ++c) {
      b0[c] = *(const short8*)&Cbs[ks][0][wcol * 2 + c][lane][0];
      b1[c] = *(const short8*)&Cbs[ks][1][wcol * 2 + c][lane][0];
      b2[c] = *(const short8*)&Cbs[ks][2][wcol * 2 + c][lane][0];
    }
#pragma unroll
    for (int r = 0; r < 4; ++r)
#pragma unroll
      for (int c = 0; c < 2; ++c) {
        f32x4 dd = acc[r][c];
        dd = mfma16(a0[r], b0[c], dd);
        dd = mfma16(a0[r], b1[c], dd);
        dd = mfma16(a1[r], b0[c], dd);
        dd = mfma16(a1[r], b1[c], dd);
        dd = mfma16(a0[r], b2[c], dd);
        dd = mfma16(a2[r], b0[c], dd);
        acc[r][c] = dd;
      }
  }
#pragma unroll
  for (int r = 0; r < 4; ++r)
#pragma unroll
    for (int c = 0; c < 2; ++c) {
      const int rl = wrow * 64 + r * 16 + (lane >> 4) * 4;
      const int cl = wcol * 32 + c * 16 + (lane & 15);
      const float cn = cnorm[cl];
#pragma unroll
      for (int i = 0; i < 4; ++i) {
        float d2 = enorm[rl + i] + cn - 2.f * acc[r][c][i];
        cost[(size_t)(r0 + rl + i) * CB + c0 + cl] = sqrtf(fmaxf(d2, 0.f));
      }
    }
}

// ---------------------------------------------------------------------------
// k_assign: one wave per sample, all-register JV with DPP reduce (unchanged).
// ---------------------------------------------------------------------------
__global__ __launch_bounds__(64, 1) void k_assign(
    const float* __restrict__ cost_g, const float* __restrict__ codebook,
    float* __restrict__ q_out, float* __restrict__ idx_out) {
  __shared__ int idxl[32];
  const int lane = threadIdx.x;
  const int s = blockIdx.x;
  const float* __restrict__ cost = cost_g + (size_t)s * NC * CB;

  double v_[16], minv_[16];
  u32 wp_[16];                        // low16 = way, high16 = pm
  double u_val = 0.0;                 // lane l holds u[l] (rows 1..32)
#pragma unroll
  for (int r = 0; r < 16; ++r) { v_[r] = 0.0; wp_[r] = 0; }

  float pf[16];
#pragma unroll
  for (int r = 0; r < 16; ++r) pf[r] = cost[r * 64 + lane];   // row 0

  for (int i = 1; i <= NC; ++i) {
#pragma unroll
    for (int r = 0; r < 16; ++r) minv_[r] = 1e300;
    u32 col_used = 0;
    unsigned long long rowmask = 0ull;
    int j0 = 0;
    int i0 = i;
    float cc[16];
#pragma unroll
    for (int r = 0; r < 16; ++r) cc[r] = pf[r];
    int first = 1;
    for (int guard = 0; guard < 1056; ++guard) {
      rowmask |= (1ull << i0);
      const double ui0 = __shfl(u_val, i0);
      if (first && i < NC) {
#pragma unroll
        for (int r = 0; r < 16; ++r)
          pf[r] = cost[(size_t)i * CB + r * 64 + lane];
      }
      first = 0;
      double bv = 1e301; int bj = 1 << 20;
#pragma unroll
      for (int r = 0; r < 16; ++r) {
        const int j = 1 + lane + r * 64;
        if (!((col_used >> r) & 1u)) {
          double cur = (double)cc[r] - ui0 - v_[r];
          if (cur < minv_[r]) { minv_[r] = cur; wp_[r] = (wp_[r] & 0xFFFF0000u) | (u32)j0; }
          if (minv_[r] < bv) { bv = minv_[r]; bj = j; }
        }
      }
      { double ov = dpp_f64<0xB1>(bv);  int oj = dpp_i32<0xB1>(bj);
        if (ov < bv || (ov == bv && oj < bj)) { bv = ov; bj = oj; } }
      { double ov = dpp_f64<0x4E>(bv);  int oj = dpp_i32<0x4E>(bj);
        if (ov < bv || (ov == bv && oj < bj)) { bv = ov; bj = oj; } }
      { double ov = dpp_f64<0x124>(bv); int oj = dpp_i32<0x124>(bj);
        if (ov < bv || (ov == bv && oj < bj)) { bv = ov; bj = oj; } }
      { double ov = dpp_f64<0x128>(bv); int oj = dpp_i32<0x128>(bj);
        if (ov < bv || (ov == bv && oj < bj)) { bv = ov; bj = oj; } }
#pragma unroll
      for (int off = 16; off < 64; off <<= 1) {
        double ov = __shfl_xor(bv, off);
        int oj = __shfl_xor(bj, off);
        if (ov < bv || (ov == bv && oj < bj)) { bv = ov; bj = oj; }
      }
      const double delta = bv;
      const int k = bj;
      const int rk = (k - 1) >> 6, kl = (k - 1) & 63;
      u32 sel = 0;
#pragma unroll
      for (int r = 0; r < 16; ++r) if (r == rk) sel = wp_[r];
      const int pmk = ((u32)__shfl((int)sel, kl)) >> 16;
      float ccn[16];
      if (pmk > 0) {
        const float* crow = cost + (size_t)(pmk - 1) * CB;
#pragma unroll
        for (int r = 0; r < 16; ++r) ccn[r] = crow[r * 64 + lane];
      }
      if ((rowmask >> lane) & 1ull) u_val += delta;
#pragma unroll
      for (int r = 0; r < 16; ++r) {
        const int j = 1 + lane + r * 64;
        if ((col_used >> r) & 1u) v_[r] -= delta;
        else {
          minv_[r] -= delta;
          if (j == k) col_used |= (1u << r);
        }
      }
      j0 = k;
      if (pmk == 0) break;
      i0 = pmk;
#pragma unroll
      for (int r = 0; r < 16; ++r) cc[r] = ccn[r];
    }
    int jj = j0;
    while (jj != 0) {
      const int rj = (jj - 1) >> 6, lj = (jj - 1) & 63;
      u32 wsel = 0;
#pragma unroll
      for (int r = 0; r < 16; ++r) if (r == rj) wsel = wp_[r];
      const int j1 = ((u32)__shfl((int)wsel, lj)) & 0xFFFFu;
      int newpm;
      if (j1 == 0) newpm = i;
      else {
        const int r1 = (j1 - 1) >> 6, l1 = (j1 - 1) & 63;
        u32 psel = 0;
#pragma unroll
        for (int r = 0; r < 16; ++r) if (r == r1) psel = wp_[r];
        newpm = ((u32)__shfl((int)psel, l1)) >> 16;
      }
#pragma unroll
      for (int r = 0; r < 16; ++r)
        if (lane == lj && r == rj) wp_[r] = (wp_[r] & 0xFFFFu) | ((u32)newpm << 16);
      jj = j1;
    }
  }

#pragma unroll
  for (int r = 0; r < 16; ++r) {
    const u32 pm = wp_[r] >> 16;
    if (pm > 0) idxl[pm - 1] = lane + r * 64;
  }
  WAVE_SYNC(); SCHED_FENCE();
  if (lane < NC) idx_out[(size_t)s * NC + lane] = (float)idxl[lane];
#pragma unroll
  for (int p = 0; p < 8; ++p) {
    int vi = p * 64 + lane;
    int r = vi >> 4, c4 = vi & 15;
    int ci = idxl[r];
    float4 qv = *(const float4*)&codebook[(size_t)ci * 64 + c4 * 4];
    *(float4*)&q_out[(size_t)s * NCD + r * 64 + c4 * 4] = qv;
  }
}

// ---------------------------------------------------------------------------
extern "C" void kernel_launch(void* const* d_in, const int* in_sizes, int n_in,
                              void* d_out, int out_size, void* d_ws, size_t ws_size,
                              hipStream_t stream) {
  (void)in_sizes; (void)n_in; (void)out_size; (void)ws_size;
  const float* x        = (const float*)d_in[0];
  const float* codebook = (const float*)d_in[1];
  const float* enc_w    = (const float*)d_in[2];
  const float* enc_b    = (const float*)d_in[3];
  const float* dec_w    = (const float*)d_in[4];
  const float* dec_b    = (const float*)d_in[5];

  float* out = (float*)d_out;
  float* r_out   = out;                       // [512][4096]
  float* q_out   = out + 2097152;             // [512][32][64]
  float* e_out   = out + 2097152 + 1048576;   // [512][32][64]
  float* idx_out = out + 2097152 + 2097152;   // [512][32] as float

  // ws layout (64 MB, phase-disjoint):
  //  phase 1: enc_w blobs [0,48M), k1 partials [48M,64M)
  //           x blobs (12M) in dead d_out regions: r_out (A1,A2), q_out (A3)
  //  phase 2: cost [0,64M)
  //  phase 3: q blob [0,2M), dec_w blob [2M,18M)
  char* ws = (char*)d_ws;
  u16* B1 = (u16*)ws;
  u16* B2 = (u16*)(ws + (16u << 20));
  u16* B3 = (u16*)(ws + (32u << 20));
  float* part = (float*)(ws + (48u << 20));
  float* cost_ws = (float*)ws;
  u16* qb  = (u16*)ws;
  u16* dwb = (u16*)(ws + (2u << 20));
  u16* A1 = (u16*)r_out;               // [0,4M) of r
  u16* A2 = (u16*)r_out + 2097152;     // [4M,8M) of r
  u16* A3 = (u16*)q_out;               // q region (4 MB exactly)

  conv_split3<HID><<<1024, 256, 0, stream>>>(x, A1, A2, A3);
  conv_split3<HID><<<4096, 256, 0, stream>>>(enc_w, B1, B2, B3);
  k1_gemm<<<dim3(4, 32, 4), 256, 0, stream>>>(A1, A2, A3, B1, B2, B3, part);
  k_reduce_bias<<<1024, 256, 0, stream>>>(part, enc_b, e_out);
  k_cost<<<dim3(128, 8), 512, 0, stream>>>(e_out, codebook, cost_ws);
  k_assign<<<BATCH, 64, 0, stream>>>(cost_ws, codebook, q_out, idx_out);
  conv_split1_dual<<<4608, 256, 0, stream>>>(dec_w, dwb, q_out, qb);
  k3_gemm<<<dim3(8, 32), 512, 0, stream>>>(qb, dwb, dec_b, r_out);
}

// Round 17
// 202.128 us; speedup vs baseline: 1.0814x; 1.0327x over previous
//
#include <hip/hip_runtime.h>
#include <hip/hip_bf16.h>
#include <stdint.h>

// Sizes
#define BATCH 512
#define HID   4096
#define NC    32
#define CD    64
#define CB    1024
#define NCD   2048   // NC*CD

typedef unsigned short u16;
typedef unsigned int   u32;
typedef unsigned long long u64;
typedef __attribute__((ext_vector_type(8))) short short8;  // 8 bf16
typedef __attribute__((ext_vector_type(4))) float f32x4;

#define WAVE_SYNC()  asm volatile("s_waitcnt lgkmcnt(0)" ::: "memory")
#define SCHED_FENCE() __builtin_amdgcn_sched_barrier(0)

__device__ inline u16 bf16_rne(float f) {
  u32 u = __builtin_bit_cast(u32, f);
  u32 r = u + 0x7FFFu + ((u >> 16) & 1u);
  return (u16)(r >> 16);
}
__device__ inline float bf16_f32(u16 h) {
  u32 u = ((u32)h) << 16;
  return __builtin_bit_cast(float, u);
}
__device__ inline void split3(float a, u16& h1, u16& h2, u16& h3) {
  h1 = bf16_rne(a);
  float r1 = a - bf16_f32(h1);
  h2 = bf16_rne(r1);
  float r2 = r1 - bf16_f32(h2);
  h3 = bf16_rne(r2);
}
__device__ inline f32x4 mfma16(short8 a, short8 b, f32x4 c) {
  return __builtin_amdgcn_mfma_f32_16x16x32_bf16(a, b, c, 0, 0, 0);
}
__device__ inline void gload_lds16(const u16* g, u16* l) {
  __builtin_amdgcn_global_load_lds(
      (const __attribute__((address_space(1))) u32*)(const void*)g,
      (__attribute__((address_space(3))) u32*)(void*)l, 16, 0, 0);
}

// DPP cross-lane movers (plain-VALU latency, no LDS round trip).
template<int CTRL>
__device__ inline double dpp_f64(double x) {
  u64 u = __builtin_bit_cast(u64, x);
  int lo = (int)(u32)u, hi = (int)(u32)(u >> 32);
  lo = __builtin_amdgcn_update_dpp(lo, lo, CTRL, 0xF, 0xF, true);
  hi = __builtin_amdgcn_update_dpp(hi, hi, CTRL, 0xF, 0xF, true);
  u64 r = ((u64)(u32)hi << 32) | (u64)(u32)lo;
  return __builtin_bit_cast(double, r);
}
template<int CTRL>
__device__ inline int dpp_i32(int x) {
  return __builtin_amdgcn_update_dpp(x, x, CTRL, 0xF, 0xF, true);
}

union H8 { u16 h[8]; short8 v; };

// ---------------------------------------------------------------------------
// conv_split3_dual: x (blocks [0,1024)) and enc_w (blocks [1024,5120)) ->
// 3 bf16 fragment-blob arrays each, one launch. K = 4096 for both sources.
// ---------------------------------------------------------------------------
__global__ __launch_bounds__(256) void conv_split3_dual(
    const float* __restrict__ s1, u16* __restrict__ d11,
    u16* __restrict__ d12, u16* __restrict__ d13,
    const float* __restrict__ s2, u16* __restrict__ d21,
    u16* __restrict__ d22, u16* __restrict__ d23) {
  __shared__ float st[4][16][36];
  const int t = threadIdx.x;
  const int wv = t >> 6, l = t & 63;
  const int bb = blockIdx.x;
  const float* src; u16 *d1, *d2, *d3; int g;
  if (bb < 1024) { src = s1; d1 = d11; d2 = d12; d3 = d13; g = bb * 4 + wv; }
  else { src = s2; d1 = d21; d2 = d22; d3 = d23; g = (bb - 1024) * 4 + wv; }
  const int rowbase = (g / 128) * 16;    // K/32 = 128
  const int kbase   = (g % 128) * 32;
  {
    const float* s = src + (size_t)(rowbase + (l >> 2)) * HID + kbase + (l & 3) * 8;
    *(f32x4*)&st[wv][l >> 2][(l & 3) * 8]     = *(const f32x4*)s;
    *(f32x4*)&st[wv][l >> 2][(l & 3) * 8 + 4] = *(const f32x4*)(s + 4);
  }
  __syncthreads();
  float vv[8];
  *(f32x4*)&vv[0] = *(const f32x4*)&st[wv][l & 15][(l >> 4) * 8];
  *(f32x4*)&vv[4] = *(const f32x4*)&st[wv][l & 15][(l >> 4) * 8 + 4];
  H8 o1, o2, o3;
#pragma unroll
  for (int i = 0; i < 8; ++i) split3(vv[i], o1.h[i], o2.h[i], o3.h[i]);
  size_t off = (size_t)g * 512 + l * 8;
  *(short8*)(d1 + off) = o1.v;
  *(short8*)(d2 + off) = o2.v;
  *(short8*)(d3 + off) = o3.v;
}

// ---------------------------------------------------------------------------
// conv_split1_dual: two f32 sources -> bf16 blobs in one launch (K=2048 both).
// ---------------------------------------------------------------------------
__global__ __launch_bounds__(256) void conv_split1_dual(
    const float* __restrict__ s1, u16* __restrict__ dst1,
    const float* __restrict__ s2, u16* __restrict__ dst2) {
  __shared__ float st[4][16][36];
  const int t = threadIdx.x;
  const int wv = t >> 6, l = t & 63;
  const int bb = blockIdx.x;
  const float* src; u16* dst; int g;
  if (bb < 4096) { src = s1; dst = dst1; g = bb * 4 + wv; }
  else           { src = s2; dst = dst2; g = (bb - 4096) * 4 + wv; }
  const int rowbase = (g / 64) * 16;     // K/32 = 64
  const int kbase   = (g % 64) * 32;
  {
    const float* s = src + (size_t)(rowbase + (l >> 2)) * 2048 + kbase + (l & 3) * 8;
    *(f32x4*)&st[wv][l >> 2][(l & 3) * 8]     = *(const f32x4*)s;
    *(f32x4*)&st[wv][l >> 2][(l & 3) * 8 + 4] = *(const f32x4*)(s + 4);
  }
  __syncthreads();
  float vv[8];
  *(f32x4*)&vv[0] = *(const f32x4*)&st[wv][l & 15][(l >> 4) * 8];
  *(f32x4*)&vv[4] = *(const f32x4*)&st[wv][l & 15][(l >> 4) * 8 + 4];
  H8 o1;
#pragma unroll
  for (int i = 0; i < 8; ++i) o1.h[i] = bf16_rne(vv[i]);
  *(short8*)(dst + (size_t)g * 512 + l * 8) = o1.v;
}

// ---------------------------------------------------------------------------
// k1_gemm: pure-blob bf16x3 6-term GEMM, 128x64 tile, split-K=4, 2 blocks/CU,
// 72 KiB dbuf, single barrier per K-step, setprio around MFMA (round 16).
// ---------------------------------------------------------------------------
__global__ __launch_bounds__(256, 2) void k1_gemm(
    const u16* __restrict__ A1, const u16* __restrict__ A2,
    const u16* __restrict__ A3,
    const u16* __restrict__ B1, const u16* __restrict__ B2,
    const u16* __restrict__ B3, float* __restrict__ part) {
  __shared__ u16 lds_all[2][36 * 512];
  const int t = threadIdx.x;
  const int wid = t >> 6, lane = t & 63;      // 4 waves
  const int wrow = wid >> 1, wcol = wid & 1;  // 2x2 wave grid
  const int d = blockIdx.x + (blockIdx.y << 2) + (blockIdx.z << 7);  // 0..511
  const int xcd = d & 7, sl = d >> 3;            // sl 0..63
  const int panel = (xcd << 4) + (sl >> 2);      // 0..127
  const int bm = (sl & 3) * 128;
  const int bn_t = panel & 31;                   // 64-col tile id
  const int kz = panel >> 5;                     // 0..3
  const int ks0 = kz * 32;                       // 32 ksteps per kz

  const u16* gp[9];
#pragma unroll
  for (int i = 0; i < 9; ++i) {
    const int b = wid + 4 * i;
    const u16* base;
    size_t frag;
    if (b < 24) {
      const int s = b >> 3, rf = b & 7;
      base = (s == 0) ? A1 : (s == 1) ? A2 : A3;
      frag = (size_t)((bm >> 4) + rf);
    } else {
      const int bb = b - 24;
      const int s = bb >> 2, cf = bb & 3;
      base = (s == 0) ? B1 : (s == 1) ? B2 : B3;
      frag = (size_t)(bn_t * 4 + cf);
    }
    gp[i] = base + (frag * 128 + ks0) * 512 + lane * 8;
  }

  f32x4 acc[4][2];
#pragma unroll
  for (int r = 0; r < 4; ++r)
#pragma unroll
    for (int c = 0; c < 2; ++c) acc[r][c] = (f32x4)0.f;

#pragma unroll
  for (int i = 0; i < 9; ++i) {
    gload_lds16(gp[i], &lds_all[0][(wid + 4 * i) * 512]);
    gp[i] += 512;
  }
  __syncthreads();

  for (int ks = 0; ks < 32; ++ks) {
    const int cur = ks & 1, nxt = cur ^ 1;
    if (ks < 31) {
#pragma unroll
      for (int i = 0; i < 9; ++i) {
        gload_lds16(gp[i], &lds_all[nxt][(wid + 4 * i) * 512]);
        gp[i] += 512;
      }
    }
    short8 b0[2], b1[2], b2[2];
#pragma unroll
    for (int c = 0; c < 2; ++c) {
      const int cf = wcol * 2 + c;
      b0[c] = *(const short8*)&lds_all[cur][(24 + 0 * 4 + cf) * 512 + lane * 8];
      b1[c] = *(const short8*)&lds_all[cur][(24 + 1 * 4 + cf) * 512 + lane * 8];
      b2[c] = *(const short8*)&lds_all[cur][(24 + 2 * 4 + cf) * 512 + lane * 8];
    }
    __builtin_amdgcn_s_setprio(1);
#pragma unroll
    for (int r = 0; r < 4; ++r) {
      const int rf = wrow * 4 + r;
      short8 a0 = *(const short8*)&lds_all[cur][(0 * 8 + rf) * 512 + lane * 8];
      short8 a1 = *(const short8*)&lds_all[cur][(1 * 8 + rf) * 512 + lane * 8];
      short8 a2 = *(const short8*)&lds_all[cur][(2 * 8 + rf) * 512 + lane * 8];
#pragma unroll
      for (int c = 0; c < 2; ++c) {
        f32x4 dd = acc[r][c];
        dd = mfma16(a0, b0[c], dd);
        dd = mfma16(a0, b1[c], dd);
        dd = mfma16(a1, b0[c], dd);
        dd = mfma16(a1, b1[c], dd);
        dd = mfma16(a0, b2[c], dd);
        dd = mfma16(a2, b0[c], dd);
        acc[r][c] = dd;
      }
    }
    __builtin_amdgcn_s_setprio(0);
    __syncthreads();
  }
  float* P = part + (size_t)kz * BATCH * NCD;
#pragma unroll
  for (int r = 0; r < 4; ++r)
#pragma unroll
    for (int c = 0; c < 2; ++c) {
      int row = bm + wrow * 64 + r * 16 + (lane >> 4) * 4;
      int col = bn_t * 64 + wcol * 32 + c * 16 + (lane & 15);
#pragma unroll
      for (int i = 0; i < 4; ++i)
        P[(size_t)(row + i) * NCD + col] = acc[r][c][i];
    }
}

// ---------------------------------------------------------------------------
__global__ __launch_bounds__(256) void k_reduce_bias(
    const float* __restrict__ part, const float* __restrict__ bias,
    float* __restrict__ e) {
  size_t o = ((size_t)blockIdx.x * 256 + threadIdx.x) * 4;
  int n = (int)(o & (NCD - 1));
  f32x4 s = *(const f32x4*)(part + o);
  s += *(const f32x4*)(part + (size_t)1 * BATCH * NCD + o);
  s += *(const f32x4*)(part + (size_t)2 * BATCH * NCD + o);
  s += *(const f32x4*)(part + (size_t)3 * BATCH * NCD + o);
  s += *(const f32x4*)(bias + n);
  *(f32x4*)(e + o) = s;
}

// ---------------------------------------------------------------------------
// k3_gemm: triple-buffered counted-vmcnt pipeline (validated round 14).
// ---------------------------------------------------------------------------
__global__ __launch_bounds__(512) void k3_gemm(
    const u16* __restrict__ Ab, const u16* __restrict__ Bb,
    const float* __restrict__ bias, float* __restrict__ C) {
  __shared__ u16 As[3][4][64][8];
  __shared__ u16 Bs[3][8][64][8];
  const int t = threadIdx.x;
  const int wid = t >> 6, lane = t & 63;
  const int wrow = wid >> 2, wcol = wid & 3;
  const int d = blockIdx.x + (blockIdx.y << 3);
  const int xcd = d & 7, sl = d >> 3;            // sl 0..31
  const int bn = ((xcd << 2) + (sl >> 3)) * 128; // 32 panels, 4 per XCD
  const int bm = (sl & 7) * 64;

  const size_t gbB = ((size_t)(bn >> 4) + wid) * 64;
  const size_t gaA = ((size_t)(bm >> 4) + wid) * 64;

  f32x4 acc[2][2];
#pragma unroll
  for (int r = 0; r < 2; ++r)
#pragma unroll
    for (int c = 0; c < 2; ++c) acc[r][c] = (f32x4)0.f;

#pragma unroll
  for (int p = 0; p < 2; ++p) {
    gload_lds16(Bb + (gbB + p) * 512 + lane * 8, &Bs[p][wid][0][0]);
    if (wid < 4)
      gload_lds16(Ab + (gaA + p) * 512 + lane * 8, &As[p][wid][0][0]);
  }

  for (int ks = 0; ks < 64; ++ks) {
    if (ks < 63) {
      if (wid < 4) asm volatile("s_waitcnt vmcnt(2)" ::: "memory");
      else         asm volatile("s_waitcnt vmcnt(1)" ::: "memory");
    } else {
      asm volatile("s_waitcnt vmcnt(0)" ::: "memory");
    }
    __builtin_amdgcn_s_barrier();
    SCHED_FENCE();
    if (ks < 62) {
      const int nb = (ks + 2) % 3;
      gload_lds16(Bb + (gbB + ks + 2) * 512 + lane * 8, &Bs[nb][wid][0][0]);
      if (wid < 4)
        gload_lds16(Ab + (gaA + ks + 2) * 512 + lane * 8, &As[nb][wid][0][0]);
    }
    const int cur = ks % 3;
    short8 a[2], b[2];
#pragma unroll
    for (int r = 0; r < 2; ++r) a[r] = *(const short8*)&As[cur][wrow * 2 + r][lane][0];
#pragma unroll
    for (int c = 0; c < 2; ++c) b[c] = *(const short8*)&Bs[cur][wcol * 2 + c][lane][0];
#pragma unroll
    for (int r = 0; r < 2; ++r)
#pragma unroll
      for (int c = 0; c < 2; ++c) acc[r][c] = mfma16(a[r], b[c], acc[r][c]);
  }
#pragma unroll
  for (int r = 0; r < 2; ++r)
#pragma unroll
    for (int c = 0; c < 2; ++c) {
      int row = bm + wrow * 32 + r * 16 + (lane >> 4) * 4;
      int col = bn + wcol * 32 + c * 16 + (lane & 15);
      float bb = bias[col];
#pragma unroll
      for (int i = 0; i < 4; ++i)
        C[(size_t)(row + i) * HID + col] = acc[r][c][i] + bb;
    }
}

// ---------------------------------------------------------------------------
// k_cost (MFMA): 6-term bf16x3 over K=64 (unchanged).
// ---------------------------------------------------------------------------
__global__ __launch_bounds__(512) void k_cost(
    const float* __restrict__ e_glob,     // [16384][64]
    const float* __restrict__ codebook,   // [1024][64]
    float* __restrict__ cost) {           // [16384][1024]
  __shared__ u16 Ea[2][3][8][64][8];
  __shared__ u16 Cbs[2][3][8][64][8];
  __shared__ float enorm[128], cnorm[128];
  const int t = threadIdx.x;
  const int wid = t >> 6, lane = t & 63;
  const int wrow = wid >> 2, wcol = wid & 3;
  const int r0 = blockIdx.x * 128;
  const int c0 = blockIdx.y * 128;

  {
    const int fr = lane & 15, kc = lane >> 4;
    const float* ea = e_glob   + (size_t)(r0 + wid * 16 + fr) * CD + kc * 8;
    const float* cb = codebook + (size_t)(c0 + wid * 16 + fr) * CD + kc * 8;
#pragma unroll
    for (int ks = 0; ks < 2; ++ks) {
      float va[8], vb[8];
      *(f32x4*)&va[0] = *(const f32x4*)(ea + ks * 32);
      *(f32x4*)&va[4] = *(const f32x4*)(ea + ks * 32 + 4);
      *(f32x4*)&vb[0] = *(const f32x4*)(cb + ks * 32);
      *(f32x4*)&vb[4] = *(const f32x4*)(cb + ks * 32 + 4);
      H8 a1, a2, a3, b1, b2, b3;
#pragma unroll
      for (int i = 0; i < 8; ++i) {
        split3(va[i], a1.h[i], a2.h[i], a3.h[i]);
        split3(vb[i], b1.h[i], b2.h[i], b3.h[i]);
      }
      *(short8*)&Ea[ks][0][wid][lane][0] = a1.v;
      *(short8*)&Ea[ks][1][wid][lane][0] = a2.v;
      *(short8*)&Ea[ks][2][wid][lane][0] = a3.v;
      *(short8*)&Cbs[ks][0][wid][lane][0] = b1.v;
      *(short8*)&Cbs[ks][1][wid][lane][0] = b2.v;
      *(short8*)&Cbs[ks][2][wid][lane][0] = b3.v;
    }
  }
  if (t < 256) {
    const int which = t >> 7, idx = t & 127;
    const float* p = which ? codebook + (size_t)(c0 + idx) * CD
                           : e_glob   + (size_t)(r0 + idx) * CD;
    float s = 0.f;
#pragma unroll
    for (int k = 0; k < 16; ++k) {
      f32x4 v = *(const f32x4*)(p + k * 4);
      s += v.x * v.x + v.y * v.y + v.z * v.z + v.w * v.w;
    }
    if (which) cnorm[idx] = s; else enorm[idx] = s;
  }
  __syncthreads();

  f32x4 acc[4][2];
#pragma unroll
  for (int r = 0; r < 4; ++r)
#pragma unroll
    for (int c = 0; c < 2; ++c) acc[r][c] = (f32x4)0.f;
#pragma unroll
  for (int ks = 0; ks < 2; ++ks) {
    short8 a0[4], a1[4], a2[4], b0[2], b1[2], b2[2];
#pragma unroll
    for (int r = 0; r < 4; ++r) {
      a0[r] = *(const short8*)&Ea[ks][0][wrow * 4 + r][lane][0];
      a1[r] = *(const short8*)&Ea[ks][1][wrow * 4 + r][lane][0];
      a2[r] = *(const short8*)&Ea[ks][2][wrow * 4 + r][lane][0];
    }
#pragma unroll
    for (int c = 0; c < 2; ++c) {
      b0[c] = *(const short8*)&Cbs[ks][0][wcol * 2 + c][lane][0];
      b1[c] = *(const short8*)&Cbs[ks][1][wcol * 2 + c][lane][0];
      b2[c] = *(const short8*)&Cbs[ks][2][wcol * 2 + c][lane][0];
    }
#pragma unroll
    for (int r = 0; r < 4; ++r)
#pragma unroll
      for (int c = 0; c < 2; ++c) {
        f32x4 dd = acc[r][c];
        dd = mfma16(a0[r], b0[c], dd);
        dd = mfma16(a0[r], b1[c], dd);
        dd = mfma16(a1[r], b0[c], dd);
        dd = mfma16(a1[r], b1[c], dd);
        dd = mfma16(a0[r], b2[c], dd);
        dd = mfma16(a2[r], b0[c], dd);
        acc[r][c] = dd;
      }
  }
#pragma unroll
  for (int r = 0; r < 4; ++r)
#pragma unroll
    for (int c = 0; c < 2; ++c) {
      const int rl = wrow * 64 + r * 16 + (lane >> 4) * 4;
      const int cl = wcol * 32 + c * 16 + (lane & 15);
      const float cn = cnorm[cl];
#pragma unroll
      for (int i = 0; i < 4; ++i) {
        float d2 = enorm[rl + i] + cn - 2.f * acc[r][c][i];
        cost[(size_t)(r0 + rl + i) * CB + c0 + cl] = sqrtf(fmaxf(d2, 0.f));
      }
    }
}

// ---------------------------------------------------------------------------
// k_assign: one wave per sample, all-register JV. Round-17: two-phase exact
// reduce — (1) f64 value-min over the DPP/shfl network, (2) i32 index-min
// among lanes holding the min. Same (delta, k) as the fused lexicographic
// reduce: per-lane bj is already the lane's smallest-j argmin, so the min of
// {bj : bv==gmin} is the global smallest-j argmin. +-0.0 ties compare equal.
// ---------------------------------------------------------------------------
__global__ __launch_bounds__(64, 1) void k_assign(
    const float* __restrict__ cost_g, const float* __restrict__ codebook,
    float* __restrict__ q_out, float* __restrict__ idx_out) {
  __shared__ int idxl[32];
  const int lane = threadIdx.x;
  const int s = blockIdx.x;
  const float* __restrict__ cost = cost_g + (size_t)s * NC * CB;

  double v_[16], minv_[16];
  u32 wp_[16];                        // low16 = way, high16 = pm
  double u_val = 0.0;                 // lane l holds u[l] (rows 1..32)
#pragma unroll
  for (int r = 0; r < 16; ++r) { v_[r] = 0.0; wp_[r] = 0; }

  float pf[16];
#pragma unroll
  for (int r = 0; r < 16; ++r) pf[r] = cost[r * 64 + lane];   // row 0

  for (int i = 1; i <= NC; ++i) {
#pragma unroll
    for (int r = 0; r < 16; ++r) minv_[r] = 1e300;
    u32 col_used = 0;
    unsigned long long rowmask = 0ull;
    int j0 = 0;
    int i0 = i;
    float cc[16];
#pragma unroll
    for (int r = 0; r < 16; ++r) cc[r] = pf[r];
    int first = 1;
    for (int guard = 0; guard < 1056; ++guard) {
      rowmask |= (1ull << i0);
      const double ui0 = __shfl(u_val, i0);
      if (first && i < NC) {
#pragma unroll
        for (int r = 0; r < 16; ++r)
          pf[r] = cost[(size_t)i * CB + r * 64 + lane];
      }
      first = 0;
      double bv = 1e301; int bj = 1 << 20;
#pragma unroll
      for (int r = 0; r < 16; ++r) {
        const int j = 1 + lane + r * 64;
        if (!((col_used >> r) & 1u)) {
          double cur = (double)cc[r] - ui0 - v_[r];
          if (cur < minv_[r]) { minv_[r] = cur; wp_[r] = (wp_[r] & 0xFFFF0000u) | (u32)j0; }
          if (minv_[r] < bv) { bv = minv_[r]; bj = j; }
        }
      }
      // phase 1: pure f64 value-min across 64 lanes
      double gm = bv;
      { double ov = dpp_f64<0xB1>(gm);  if (ov < gm) gm = ov; }
      { double ov = dpp_f64<0x4E>(gm);  if (ov < gm) gm = ov; }
      { double ov = dpp_f64<0x124>(gm); if (ov < gm) gm = ov; }
      { double ov = dpp_f64<0x128>(gm); if (ov < gm) gm = ov; }
      { double ov = __shfl_xor(gm, 16); if (ov < gm) gm = ov; }
      { double ov = __shfl_xor(gm, 32); if (ov < gm) gm = ov; }
      // phase 2: i32 index-min among lanes holding the min
      int cj = (bv == gm) ? bj : (1 << 20);
      { int oj = dpp_i32<0xB1>(cj);  if (oj < cj) cj = oj; }
      { int oj = dpp_i32<0x4E>(cj);  if (oj < cj) cj = oj; }
      { int oj = dpp_i32<0x124>(cj); if (oj < cj) cj = oj; }
      { int oj = dpp_i32<0x128>(cj); if (oj < cj) cj = oj; }
      { int oj = __shfl_xor(cj, 16); if (oj < cj) cj = oj; }
      { int oj = __shfl_xor(cj, 32); if (oj < cj) cj = oj; }
      const double delta = gm;
      const int k = cj;
      const int rk = (k - 1) >> 6, kl = (k - 1) & 63;
      u32 sel = 0;
#pragma unroll
      for (int r = 0; r < 16; ++r) if (r == rk) sel = wp_[r];
      const int pmk = ((u32)__shfl((int)sel, kl)) >> 16;
      float ccn[16];
      if (pmk > 0) {
        const float* crow = cost + (size_t)(pmk - 1) * CB;
#pragma unroll
        for (int r = 0; r < 16; ++r) ccn[r] = crow[r * 64 + lane];
      }
      if ((rowmask >> lane) & 1ull) u_val += delta;
#pragma unroll
      for (int r = 0; r < 16; ++r) {
        const int j = 1 + lane + r * 64;
        if ((col_used >> r) & 1u) v_[r] -= delta;
        else {
          minv_[r] -= delta;
          if (j == k) col_used |= (1u << r);
        }
      }
      j0 = k;
      if (pmk == 0) break;
      i0 = pmk;
#pragma unroll
      for (int r = 0; r < 16; ++r) cc[r] = ccn[r];
    }
    int jj = j0;
    while (jj != 0) {
      const int rj = (jj - 1) >> 6, lj = (jj - 1) & 63;
      u32 wsel = 0;
#pragma unroll
      for (int r = 0; r < 16; ++r) if (r == rj) wsel = wp_[r];
      const int j1 = ((u32)__shfl((int)wsel, lj)) & 0xFFFFu;
      int newpm;
      if (j1 == 0) newpm = i;
      else {
        const int r1 = (j1 - 1) >> 6, l1 = (j1 - 1) & 63;
        u32 psel = 0;
#pragma unroll
        for (int r = 0; r < 16; ++r) if (r == r1) psel = wp_[r];
        newpm = ((u32)__shfl((int)psel, l1)) >> 16;
      }
#pragma unroll
      for (int r = 0; r < 16; ++r)
        if (lane == lj && r == rj) wp_[r] = (wp_[r] & 0xFFFFu) | ((u32)newpm << 16);
      jj = j1;
    }
  }

#pragma unroll
  for (int r = 0; r < 16; ++r) {
    const u32 pm = wp_[r] >> 16;
    if (pm > 0) idxl[pm - 1] = lane + r * 64;
  }
  WAVE_SYNC(); SCHED_FENCE();
  if (lane < NC) idx_out[(size_t)s * NC + lane] = (float)idxl[lane];
#pragma unroll
  for (int p = 0; p < 8; ++p) {
    int vi = p * 64 + lane;
    int r = vi >> 4, c4 = vi & 15;
    int ci = idxl[r];
    float4 qv = *(const float4*)&codebook[(size_t)ci * 64 + c4 * 4];
    *(float4*)&q_out[(size_t)s * NCD + r * 64 + c4 * 4] = qv;
  }
}

// ---------------------------------------------------------------------------
extern "C" void kernel_launch(void* const* d_in, const int* in_sizes, int n_in,
                              void* d_out, int out_size, void* d_ws, size_t ws_size,
                              hipStream_t stream) {
  (void)in_sizes; (void)n_in; (void)out_size; (void)ws_size;
  const float* x        = (const float*)d_in[0];
  const float* codebook = (const float*)d_in[1];
  const float* enc_w    = (const float*)d_in[2];
  const float* enc_b    = (const float*)d_in[3];
  const float* dec_w    = (const float*)d_in[4];
  const float* dec_b    = (const float*)d_in[5];

  float* out = (float*)d_out;
  float* r_out   = out;                       // [512][4096]
  float* q_out   = out + 2097152;             // [512][32][64]
  float* e_out   = out + 2097152 + 1048576;   // [512][32][64]
  float* idx_out = out + 2097152 + 2097152;   // [512][32] as float

  // ws layout (64 MB, phase-disjoint):
  //  phase 1: enc_w blobs [0,48M), k1 partials [48M,64M)
  //           x blobs (12M) in dead d_out regions: r_out (A1,A2), q_out (A3)
  //  phase 2: cost [0,64M)
  //  phase 3: q blob [0,2M), dec_w blob [2M,18M)
  char* ws = (char*)d_ws;
  u16* B1 = (u16*)ws;
  u16* B2 = (u16*)(ws + (16u << 20));
  u16* B3 = (u16*)(ws + (32u << 20));
  float* part = (float*)(ws + (48u << 20));
  float* cost_ws = (float*)ws;
  u16* qb  = (u16*)ws;
  u16* dwb = (u16*)(ws + (2u << 20));
  u16* A1 = (u16*)r_out;               // [0,4M) of r
  u16* A2 = (u16*)r_out + 2097152;     // [4M,8M) of r
  u16* A3 = (u16*)q_out;               // q region (4 MB exactly)

  conv_split3_dual<<<5120, 256, 0, stream>>>(x, A1, A2, A3, enc_w, B1, B2, B3);
  k1_gemm<<<dim3(4, 32, 4), 256, 0, stream>>>(A1, A2, A3, B1, B2, B3, part);
  k_reduce_bias<<<1024, 256, 0, stream>>>(part, enc_b, e_out);
  k_cost<<<dim3(128, 8), 512, 0, stream>>>(e_out, codebook, cost_ws);
  k_assign<<<BATCH, 64, 0, stream>>>(cost_ws, codebook, q_out, idx_out);
  conv_split1_dual<<<4608, 256, 0, stream>>>(dec_w, dwb, q_out, qb);
  k3_gemm<<<dim3(8, 32), 512, 0, stream>>>(qb, dwb, dec_b, r_out);
}